// Round 1
// baseline (478.879 us; speedup 1.0000x reference)
//
#include <hip/hip_runtime.h>

// Problem constants (match reference)
constexpr int NXc = 100, NYc = 100, NZc = 10;
constexpr int NVOX = NZc * NYc * NXc;      // 100000
constexpr int CO = 256, CG = 48;
constexpr int BT = 2;
constexpr int NPT = 6 * 32 * 88;           // 16896 points per bt
constexpr float GMX = -40.0f, GMY = -40.0f, GMZ = -2.0f;
constexpr float VOXEL = 0.8f;

// ---------------------------------------------------------------------------
// Pass 1: scatter-add 48-dim features + counts into ws.
// One thread per (point, channel). Exact-match f32 division/floor vs ref.
// ---------------------------------------------------------------------------
__global__ __launch_bounds__(256) void k_scatter(
    const float* __restrict__ pts, const float* __restrict__ feats,
    float* __restrict__ sum48, float* __restrict__ cnt)
{
    int idx = blockIdx.x * 256 + threadIdx.x;   // (bt*NPT + n)*CG + k
    int k  = idx % CG;
    int pn = idx / CG;
    float x = pts[pn * 3 + 0];
    float y = pts[pn * 3 + 1];
    float z = pts[pn * 3 + 2];
    int ix = (int)floorf((x - GMX) / VOXEL);
    int iy = (int)floorf((y - GMY) / VOXEL);
    int iz = (int)floorf((z - GMZ) / VOXEL);
    bool valid = (ix >= 0 && ix < NXc && iy >= 0 && iy < NYc && iz >= 0 && iz < NZc);
    if (!valid) return;
    int bt  = pn / NPT;
    int lin = iz * (NYc * NXc) + iy * NXc + ix;
    atomicAdd(&sum48[((size_t)(bt * NVOX + lin)) * CG + k], feats[idx]);
    if (k == 0) atomicAdd(&cnt[bt * NVOX + lin], 1.0f);
}

// ---------------------------------------------------------------------------
// Pass 2: project occ_volume 256 -> 48 channels: P[bt][vox][g].
// Coalesced read of the full 205 MB volume; 2 voxels per thread for pk-math.
// ---------------------------------------------------------------------------
__global__ __launch_bounds__(128) void k_volproj(
    const float* __restrict__ occ, const float* __restrict__ Wo2g,
    float* __restrict__ P)
{
    __shared__ float Wl[CO * CG];
    for (int j = threadIdx.x; j < CO * CG; j += 128) Wl[j] = Wo2g[j];
    __syncthreads();
    int v2 = blockIdx.x * 256 + threadIdx.x * 2;
    int bt = blockIdx.y;
    if (v2 >= NVOX) return;
    const float* base = occ + (size_t)bt * CO * NVOX + v2;
    float ax[CG], ay[CG];
#pragma unroll
    for (int g = 0; g < CG; ++g) { ax[g] = 0.f; ay[g] = 0.f; }
#pragma unroll 2
    for (int c = 0; c < CO; ++c) {
        float2 ov = *reinterpret_cast<const float2*>(base + (size_t)c * NVOX);
        const float* w = &Wl[c * CG];
#pragma unroll
        for (int g = 0; g < CG; ++g) {
            ax[g] = fmaf(ov.x, w[g], ax[g]);
            ay[g] = fmaf(ov.y, w[g], ay[g]);
        }
    }
    float* o = P + ((size_t)bt * NVOX + v2) * CG;
#pragma unroll
    for (int g = 0; g < CG; ++g) o[g] = ax[g];
#pragma unroll
    for (int g = 0; g < CG; ++g) o[CG + g] = ay[g];
}

// ---------------------------------------------------------------------------
// Pass 3: trilinear gather from P + bias -> occ_to_gs output.
// One thread per (point, out-channel g). Corner rows are contiguous 192 B.
// ---------------------------------------------------------------------------
__global__ __launch_bounds__(256) void k_gather(
    const float* __restrict__ pts, const float* __restrict__ P,
    const float* __restrict__ bo2g, float* __restrict__ out1)
{
    int idx = blockIdx.x * 256 + threadIdx.x;   // (bt*NPT+n)*CG + g
    int g  = idx % CG;
    int pn = idx / CG;
    int bt = pn / NPT;
    float x = pts[pn * 3 + 0];
    float y = pts[pn * 3 + 1];
    float z = pts[pn * 3 + 2];
    // mirror reference: g = (p-min)/dims*2-1 ; pix = ((g+1)*size-1)*0.5
    float gx = (x - GMX) / 80.0f * 2.0f - 1.0f;
    float gy = (y - GMY) / 80.0f * 2.0f - 1.0f;
    float gz = (z - GMZ) / 8.0f  * 2.0f - 1.0f;
    float px = ((gx + 1.0f) * (float)NXc - 1.0f) * 0.5f;
    float py = ((gy + 1.0f) * (float)NYc - 1.0f) * 0.5f;
    float pz = ((gz + 1.0f) * (float)NZc - 1.0f) * 0.5f;
    float fx = floorf(px), fy = floorf(py), fz = floorf(pz);
    float rx = px - fx, ry = py - fy, rz = pz - fz;
    int x0 = (int)fx, y0 = (int)fy, z0 = (int)fz;
    float acc = bo2g[g];
    const float* Pb = P + (size_t)bt * NVOX * CG;
#pragma unroll
    for (int dz = 0; dz <= 1; ++dz) {
        int zi = z0 + dz;
        if (zi < 0 || zi >= NZc) continue;
        float wz = dz ? rz : 1.0f - rz;
#pragma unroll
        for (int dy = 0; dy <= 1; ++dy) {
            int yi = y0 + dy;
            if (yi < 0 || yi >= NYc) continue;
            float wy = dy ? ry : 1.0f - ry;
#pragma unroll
            for (int dx = 0; dx <= 1; ++dx) {
                int xi = x0 + dx;
                if (xi < 0 || xi >= NXc) continue;
                float wx = dx ? rx : 1.0f - rx;
                float w = (wx * wy) * wz;
                int lin = zi * (NYc * NXc) + yi * NXc + xi;
                acc = fmaf(w, Pb[(size_t)lin * CG + g], acc);
            }
        }
    }
    out1[idx] = acc;
}

// ---------------------------------------------------------------------------
// Pass 4: write gs_to_occ (channel-first). Block = 64 vox x 256 channels.
// Wave lanes span 64 consecutive vox at fixed c -> coalesced 256 B stores.
// Empty voxels (84%) write 0 without compute.
// ---------------------------------------------------------------------------
__global__ __launch_bounds__(256) void k_out0(
    const float* __restrict__ sum48, const float* __restrict__ cnt,
    const float* __restrict__ Wg2o, const float* __restrict__ bg2o,
    float* __restrict__ out0)
{
    __shared__ float Wt[CO * CG];     // Wt[c*48+k] = Wg2o[k*256+c]
    __shared__ float sm[64 * 49];     // padded stride 49 (bank-conflict)
    __shared__ float sc[64];
    int bt   = blockIdx.y;
    int voxb = blockIdx.x * 64;
    for (int j = threadIdx.x; j < CO * CG; j += 256) {
        int k = j >> 8, c = j & 255;
        Wt[c * CG + k] = Wg2o[j];
    }
    for (int j = threadIdx.x; j < 64 * CG; j += 256) {
        int v = j / CG, k = j - v * CG;
        int vox = voxb + v;
        sm[v * 49 + k] = (vox < NVOX) ? sum48[((size_t)(bt * NVOX + vox)) * CG + k] : 0.f;
    }
    if (threadIdx.x < 64) {
        int vox = voxb + threadIdx.x;
        sc[threadIdx.x] = (vox < NVOX) ? cnt[bt * NVOX + vox] : 0.f;
    }
    __syncthreads();
    int vl = threadIdx.x & 63;
    int c0 = threadIdx.x >> 6;
    int vox = voxb + vl;
    if (vox >= NVOX) return;
    float cv = sc[vl];
    float* ob = out0 + (size_t)bt * CO * NVOX + vox;
    if (cv > 0.f) {
        float inv = 1.0f / cv;
        float m[CG];
#pragma unroll
        for (int k = 0; k < CG; ++k) m[k] = sm[vl * 49 + k] * inv;
        for (int c = c0; c < CO; c += 4) {
            float a = bg2o[c];
            const float4* w4 = reinterpret_cast<const float4*>(&Wt[c * CG]);
#pragma unroll
            for (int q = 0; q < CG / 4; ++q) {
                float4 w = w4[q];
                a = fmaf(m[4 * q + 0], w.x, a);
                a = fmaf(m[4 * q + 1], w.y, a);
                a = fmaf(m[4 * q + 2], w.z, a);
                a = fmaf(m[4 * q + 3], w.w, a);
            }
            ob[(size_t)c * NVOX] = a;
        }
    } else {
        for (int c = c0; c < CO; c += 4) ob[(size_t)c * NVOX] = 0.f;
    }
}

// ---------------------------------------------------------------------------
extern "C" void kernel_launch(void* const* d_in, const int* in_sizes, int n_in,
                              void* d_out, int out_size, void* d_ws, size_t ws_size,
                              hipStream_t stream)
{
    const float* centers = (const float*)d_in[0];
    const float* feats   = (const float*)d_in[1];
    const float* occ     = (const float*)d_in[2];
    const float* Wg2o    = (const float*)d_in[3];
    const float* bg2o    = (const float*)d_in[4];
    const float* Wo2g    = (const float*)d_in[5];
    const float* bo2g    = (const float*)d_in[6];

    float* out  = (float*)d_out;
    float* out0 = out;                                   // [BT][CO][NVOX] = 51.2M floats
    float* out1 = out + (size_t)BT * CO * NVOX;          // [BT][NPT][CG]
    // P lives in the tail of out0's region: written by pass2, read by pass3,
    // overwritten by pass4 (stream-ordered, so safe; saves 38 MB of ws).
    float* P    = out0 + (size_t)BT * CO * NVOX - (size_t)BT * NVOX * CG;

    float* sum48 = (float*)d_ws;                         // BT*NVOX*CG floats
    float* cntp  = sum48 + (size_t)BT * NVOX * CG;       // BT*NVOX floats
    size_t zbytes = ((size_t)BT * NVOX * CG + (size_t)BT * NVOX) * sizeof(float);
    hipMemsetAsync(d_ws, 0, zbytes, stream);

    int totPK = BT * NPT * CG;                           // 1,622,016 (divisible by 256)
    k_scatter<<<totPK / 256, 256, 0, stream>>>(centers, feats, sum48, cntp);
    k_volproj<<<dim3((NVOX + 255) / 256, BT), 128, 0, stream>>>(occ, Wo2g, P);
    k_gather<<<totPK / 256, 256, 0, stream>>>(centers, P, bo2g, out1);
    k_out0<<<dim3((NVOX + 63) / 64, BT), 256, 0, stream>>>(sum48, cntp, Wg2o, bg2o, out0);
}

// Round 3
// 282.124 us; speedup vs baseline: 1.6974x; 1.6974x over previous
//
#include <hip/hip_runtime.h>

typedef float v4f __attribute__((ext_vector_type(4)));

// Problem constants (match reference)
constexpr int NXc = 100, NYc = 100, NZc = 10;
constexpr int NVOX = NZc * NYc * NXc;      // 100000
constexpr int CO = 256, CG = 48;
constexpr int BT = 2;
constexpr int NPT = 6 * 32 * 88;           // 16896 points per bt
constexpr int NPTS = BT * NPT;             // 33792
constexpr int MAXS = NPTS;                 // max occupied voxels
constexpr float GMX = -40.0f, GMY = -40.0f, GMZ = -2.0f;
constexpr float VOXEL = 0.8f;

// ---------------------------------------------------------------------------
// Pass 1: per point -> voxel; count + assign compact slots.
// ---------------------------------------------------------------------------
__global__ __launch_bounds__(256) void k_count(
    const float* __restrict__ pts, float* __restrict__ cnt,
    int* __restrict__ nocc, int* __restrict__ invmap, int* __restrict__ ptvox)
{
    int pn = blockIdx.x * 256 + threadIdx.x;      // < NPTS (exact grid)
    float x = pts[pn * 3 + 0];
    float y = pts[pn * 3 + 1];
    float z = pts[pn * 3 + 2];
    int ix = (int)floorf((x - GMX) / VOXEL);
    int iy = (int)floorf((y - GMY) / VOXEL);
    int iz = (int)floorf((z - GMZ) / VOXEL);
    bool valid = (ix >= 0 && ix < NXc && iy >= 0 && iy < NYc && iz >= 0 && iz < NZc);
    if (!valid) { ptvox[pn] = -1; return; }
    int bt = pn / NPT;
    int btvox = bt * NVOX + iz * (NYc * NXc) + iy * NXc + ix;
    ptvox[pn] = btvox;
    float old = atomicAdd(&cnt[btvox], 1.0f);
    if (old == 0.0f) {
        int s = atomicAdd(nocc, 1);
        invmap[btvox] = s + 1;                    // 0 = empty
    }
}

// list[slot] = btvox needed by gemm for cnt lookup.
__global__ __launch_bounds__(256) void k_mklist(
    const int* __restrict__ invmap, int* __restrict__ list)
{
    int v = blockIdx.x * 256 + threadIdx.x;       // < BT*NVOX
    if (v >= BT * NVOX) return;
    int sp = invmap[v];
    if (sp) list[sp - 1] = v;
}

// ---------------------------------------------------------------------------
// Pass 2: scatter-add 48-dim features into compact mean buffer.
// ---------------------------------------------------------------------------
__global__ __launch_bounds__(256) void k_scatterM(
    const float* __restrict__ feats, const int* __restrict__ ptvox,
    const int* __restrict__ invmap, float* __restrict__ compactM)
{
    int idx = blockIdx.x * 256 + threadIdx.x;     // (pn)*CG + k, < NPTS*CG
    int k  = idx % CG;
    int pn = idx / CG;
    int bv = ptvox[pn];
    if (bv < 0) return;
    int slot = invmap[bv] - 1;
    atomicAdd(&compactM[(size_t)slot * CG + k], feats[idx]);
}

// ---------------------------------------------------------------------------
// Pass 3: project occ_volume 256 -> 48 channels: P[bt][vox][g].
// ---------------------------------------------------------------------------
__global__ __launch_bounds__(128) void k_volproj(
    const float* __restrict__ occ, const float* __restrict__ Wo2g,
    float* __restrict__ P)
{
    __shared__ float Wl[CO * CG];
    for (int j = threadIdx.x; j < CO * CG; j += 128) Wl[j] = Wo2g[j];
    __syncthreads();
    int v2 = blockIdx.x * 256 + threadIdx.x * 2;
    int bt = blockIdx.y;
    if (v2 >= NVOX) return;
    const float* base = occ + (size_t)bt * CO * NVOX + v2;
    float ax[CG], ay[CG];
#pragma unroll
    for (int g = 0; g < CG; ++g) { ax[g] = 0.f; ay[g] = 0.f; }
#pragma unroll 2
    for (int c = 0; c < CO; ++c) {
        float2 ov = *reinterpret_cast<const float2*>(base + (size_t)c * NVOX);
        const float* w = &Wl[c * CG];
#pragma unroll
        for (int g = 0; g < CG; ++g) {
            ax[g] = fmaf(ov.x, w[g], ax[g]);
            ay[g] = fmaf(ov.y, w[g], ay[g]);
        }
    }
    float* o = P + ((size_t)bt * NVOX + v2) * CG;
#pragma unroll
    for (int g = 0; g < CG; ++g) o[g] = ax[g];
#pragma unroll
    for (int g = 0; g < CG; ++g) o[CG + g] = ay[g];
}

// ---------------------------------------------------------------------------
// Pass 4: trilinear gather from P + bias -> occ_to_gs output.
// ---------------------------------------------------------------------------
__global__ __launch_bounds__(256) void k_gather(
    const float* __restrict__ pts, const float* __restrict__ P,
    const float* __restrict__ bo2g, float* __restrict__ out1)
{
    int idx = blockIdx.x * 256 + threadIdx.x;     // (pn)*CG + g
    int g  = idx % CG;
    int pn = idx / CG;
    int bt = pn / NPT;
    float x = pts[pn * 3 + 0];
    float y = pts[pn * 3 + 1];
    float z = pts[pn * 3 + 2];
    float gx = (x - GMX) / 80.0f * 2.0f - 1.0f;
    float gy = (y - GMY) / 80.0f * 2.0f - 1.0f;
    float gz = (z - GMZ) / 8.0f  * 2.0f - 1.0f;
    float px = ((gx + 1.0f) * (float)NXc - 1.0f) * 0.5f;
    float py = ((gy + 1.0f) * (float)NYc - 1.0f) * 0.5f;
    float pz = ((gz + 1.0f) * (float)NZc - 1.0f) * 0.5f;
    float fx = floorf(px), fy = floorf(py), fz = floorf(pz);
    float rx = px - fx, ry = py - fy, rz = pz - fz;
    int x0 = (int)fx, y0 = (int)fy, z0 = (int)fz;
    float acc = bo2g[g];
    const float* Pb = P + (size_t)bt * NVOX * CG;
#pragma unroll
    for (int dz = 0; dz <= 1; ++dz) {
        int zi = z0 + dz;
        if (zi < 0 || zi >= NZc) continue;
        float wz = dz ? rz : 1.0f - rz;
#pragma unroll
        for (int dy = 0; dy <= 1; ++dy) {
            int yi = y0 + dy;
            if (yi < 0 || yi >= NYc) continue;
            float wy = dy ? ry : 1.0f - ry;
#pragma unroll
            for (int dx = 0; dx <= 1; ++dx) {
                int xi = x0 + dx;
                if (xi < 0 || xi >= NXc) continue;
                float wx = dx ? rx : 1.0f - rx;
                float w = (wx * wy) * wz;
                int lin = zi * (NYc * NXc) + yi * NXc + xi;
                acc = fmaf(w, Pb[(size_t)lin * CG + g], acc);
            }
        }
    }
    out1[idx] = acc;
}

// ---------------------------------------------------------------------------
// Pass 5: sparse GEMM — compact256[slot][256] = mean[slot][48] @ Wg2o + b.
// Block = 256 thr = 4 waves; 32 slots/block (8/wave). Lane l -> c quad 4l.
// ---------------------------------------------------------------------------
__global__ __launch_bounds__(256) void k_gemm(
    const float* __restrict__ compactM, const float* __restrict__ cnt,
    const int* __restrict__ list, const int* __restrict__ noccp,
    const float* __restrict__ Wg2o, const float* __restrict__ bg2o,
    float* __restrict__ compact256)
{
    int nocc = *noccp;
    int s0 = blockIdx.x * 32;
    if (s0 >= nocc) return;                      // uniform per block
    __shared__ float Wl[CG * CO];                // 48 KB, [k][c]
    __shared__ float Ml[32 * CG];                // 6 KB means
    for (int j = threadIdx.x; j < CG * CO; j += 256) Wl[j] = Wg2o[j];
    for (int j = threadIdx.x; j < 32 * CG; j += 256) {
        int v = j / CG, k = j - v * CG;
        int slot = s0 + v;
        float m = 0.f;
        if (slot < nocc) {
            int btvox = list[slot];
            m = compactM[(size_t)slot * CG + k] / cnt[btvox];
        }
        Ml[j] = m;
    }
    __syncthreads();
    int wid = threadIdx.x >> 6, l = threadIdx.x & 63;
    int vb = wid * 8;
    float4 bias = *reinterpret_cast<const float4*>(&bg2o[4 * l]);
    float acc[8][4];
#pragma unroll
    for (int v = 0; v < 8; ++v) {
        acc[v][0] = bias.x; acc[v][1] = bias.y; acc[v][2] = bias.z; acc[v][3] = bias.w;
    }
    for (int k = 0; k < CG; k += 4) {
        float4 w0 = *reinterpret_cast<const float4*>(&Wl[(k + 0) * CO + 4 * l]);
        float4 w1 = *reinterpret_cast<const float4*>(&Wl[(k + 1) * CO + 4 * l]);
        float4 w2 = *reinterpret_cast<const float4*>(&Wl[(k + 2) * CO + 4 * l]);
        float4 w3 = *reinterpret_cast<const float4*>(&Wl[(k + 3) * CO + 4 * l]);
#pragma unroll
        for (int v = 0; v < 8; ++v) {
            float4 m4 = *reinterpret_cast<const float4*>(&Ml[(vb + v) * CG + k]);
            acc[v][0] = fmaf(m4.x, w0.x, acc[v][0]);
            acc[v][1] = fmaf(m4.x, w0.y, acc[v][1]);
            acc[v][2] = fmaf(m4.x, w0.z, acc[v][2]);
            acc[v][3] = fmaf(m4.x, w0.w, acc[v][3]);
            acc[v][0] = fmaf(m4.y, w1.x, acc[v][0]);
            acc[v][1] = fmaf(m4.y, w1.y, acc[v][1]);
            acc[v][2] = fmaf(m4.y, w1.z, acc[v][2]);
            acc[v][3] = fmaf(m4.y, w1.w, acc[v][3]);
            acc[v][0] = fmaf(m4.z, w2.x, acc[v][0]);
            acc[v][1] = fmaf(m4.z, w2.y, acc[v][1]);
            acc[v][2] = fmaf(m4.z, w2.z, acc[v][2]);
            acc[v][3] = fmaf(m4.z, w2.w, acc[v][3]);
            acc[v][0] = fmaf(m4.w, w3.x, acc[v][0]);
            acc[v][1] = fmaf(m4.w, w3.y, acc[v][1]);
            acc[v][2] = fmaf(m4.w, w3.z, acc[v][2]);
            acc[v][3] = fmaf(m4.w, w3.w, acc[v][3]);
        }
    }
#pragma unroll
    for (int v = 0; v < 8; ++v) {
        int slot = s0 + vb + v;
        if (slot < nocc) {
            float4 r; r.x = acc[v][0]; r.y = acc[v][1]; r.z = acc[v][2]; r.w = acc[v][3];
            *reinterpret_cast<float4*>(&compact256[(size_t)slot * CO + 4 * l]) = r;
        }
    }
}

// ---------------------------------------------------------------------------
// Pass 6: dense writer. Thread -> 4 consecutive vox; loop 32 channels.
// Gathers occupied values from compact256 (L1-reused lines), else 0.
// ---------------------------------------------------------------------------
__global__ __launch_bounds__(256) void k_writer(
    const int* __restrict__ invmap, const float* __restrict__ compact256,
    float* __restrict__ out0)
{
    int bt = blockIdx.z;
    int c0 = blockIdx.y * 32;
    int v0 = blockIdx.x * 1024 + threadIdx.x * 4;
    if (v0 >= NVOX) return;
    int4 sp = *reinterpret_cast<const int4*>(&invmap[bt * NVOX + v0]);
    const float* r0 = compact256 + (size_t)(sp.x - 1) * CO;
    const float* r1 = compact256 + (size_t)(sp.y - 1) * CO;
    const float* r2 = compact256 + (size_t)(sp.z - 1) * CO;
    const float* r3 = compact256 + (size_t)(sp.w - 1) * CO;
    float* ob = out0 + (size_t)bt * CO * NVOX + (size_t)c0 * NVOX + v0;
#pragma unroll 4
    for (int ci = 0; ci < 32; ++ci) {
        int c = c0 + ci;
        v4f val;
        val.x = sp.x ? r0[c] : 0.f;
        val.y = sp.y ? r1[c] : 0.f;
        val.z = sp.z ? r2[c] : 0.f;
        val.w = sp.w ? r3[c] : 0.f;
        __builtin_nontemporal_store(val, reinterpret_cast<v4f*>(ob + (size_t)ci * NVOX));
    }
}

// ---------------------------------------------------------------------------
extern "C" void kernel_launch(void* const* d_in, const int* in_sizes, int n_in,
                              void* d_out, int out_size, void* d_ws, size_t ws_size,
                              hipStream_t stream)
{
    const float* centers = (const float*)d_in[0];
    const float* feats   = (const float*)d_in[1];
    const float* occ     = (const float*)d_in[2];
    const float* Wg2o    = (const float*)d_in[3];
    const float* bg2o    = (const float*)d_in[4];
    const float* Wo2g    = (const float*)d_in[5];
    const float* bo2g    = (const float*)d_in[6];

    float* out  = (float*)d_out;
    float* out0 = out;                                   // [BT][CO][NVOX]
    float* out1 = out + (size_t)BT * CO * NVOX;          // [BT][NPT][CG]
    // P in tail of out0: written by volproj, read by gather, overwritten by writer.
    float* P    = out0 + (size_t)BT * CO * NVOX - (size_t)BT * NVOX * CG;

    // ws layout (bytes):
    char* w = (char*)d_ws;
    float* cnt       = (float*)w;                 w += (size_t)BT * NVOX * 4;       // 800000
    int*   nocc      = (int*)w;                   w += 256;
    int*   invmap    = (int*)w;                   w += (size_t)BT * NVOX * 4;       // 800000
    int*   ptvox     = (int*)w;                   w += (size_t)NPTS * 4;            // 135168
    int*   list      = (int*)w;                   w += (size_t)MAXS * 4;            // 135168
    float* compactM  = (float*)w;                 w += (size_t)MAXS * CG * 4;       // 6488064
    float* compact256= (float*)w;                 // MAXS*CO*4 = 34603008
    size_t zbytes = (size_t)BT * NVOX * 4 + 256 + (size_t)BT * NVOX * 4
                  + (size_t)NPTS * 4 + (size_t)MAXS * 4 + (size_t)MAXS * CG * 4;
    (void)hipMemsetAsync(d_ws, 0, zbytes, stream);      // ~8.4 MB

    k_count<<<NPTS / 256, 256, 0, stream>>>(centers, cnt, nocc, invmap, ptvox);
    k_mklist<<<(BT * NVOX + 255) / 256, 256, 0, stream>>>(invmap, list);
    k_scatterM<<<NPTS * CG / 256, 256, 0, stream>>>(feats, ptvox, invmap, compactM);
    k_volproj<<<dim3((NVOX + 255) / 256, BT), 128, 0, stream>>>(occ, Wo2g, P);
    k_gather<<<NPTS * CG / 256, 256, 0, stream>>>(centers, P, bo2g, out1);
    k_gemm<<<(MAXS + 31) / 32, 256, 0, stream>>>(compactM, cnt, list, nocc, Wg2o, bg2o, compact256);
    k_writer<<<dim3((NVOX + 1023) / 1024, 8, BT), 256, 0, stream>>>(invmap, compact256, out0);
}

// Round 4
// 237.072 us; speedup vs baseline: 2.0200x; 1.1900x over previous
//
#include <hip/hip_runtime.h>

typedef float v4f __attribute__((ext_vector_type(4)));

// Problem constants (match reference)
constexpr int NXc = 100, NYc = 100, NZc = 10;
constexpr int NVOX = NZc * NYc * NXc;      // 100000
constexpr int CO = 256, CG = 48;
constexpr int BT = 2;
constexpr int NPT = 6 * 32 * 88;           // 16896 points per bt
constexpr int NPTS = BT * NPT;             // 33792
constexpr int MAXS = NPTS;                 // max occupied voxels
constexpr float GMX = -40.0f, GMY = -40.0f, GMZ = -2.0f;
constexpr float VOXEL = 0.8f;

// ---------------------------------------------------------------------------
// Pass 1: per point -> voxel; count + assign compact slots.
// ---------------------------------------------------------------------------
__global__ __launch_bounds__(256) void k_count(
    const float* __restrict__ pts, float* __restrict__ cnt,
    int* __restrict__ nocc, int* __restrict__ invmap, int* __restrict__ ptvox)
{
    int pn = blockIdx.x * 256 + threadIdx.x;      // < NPTS (exact grid)
    float x = pts[pn * 3 + 0];
    float y = pts[pn * 3 + 1];
    float z = pts[pn * 3 + 2];
    int ix = (int)floorf((x - GMX) / VOXEL);
    int iy = (int)floorf((y - GMY) / VOXEL);
    int iz = (int)floorf((z - GMZ) / VOXEL);
    bool valid = (ix >= 0 && ix < NXc && iy >= 0 && iy < NYc && iz >= 0 && iz < NZc);
    if (!valid) { ptvox[pn] = -1; return; }
    int bt = pn / NPT;
    int btvox = bt * NVOX + iz * (NYc * NXc) + iy * NXc + ix;
    ptvox[pn] = btvox;
    float old = atomicAdd(&cnt[btvox], 1.0f);
    if (old == 0.0f) {
        int s = atomicAdd(nocc, 1);
        invmap[btvox] = s + 1;                    // 0 = empty
    }
}

// list[slot] = btvox needed by gemm for cnt lookup.
__global__ __launch_bounds__(256) void k_mklist(
    const int* __restrict__ invmap, int* __restrict__ list)
{
    int v = blockIdx.x * 256 + threadIdx.x;       // < BT*NVOX
    if (v >= BT * NVOX) return;
    int sp = invmap[v];
    if (sp) list[sp - 1] = v;
}

// ---------------------------------------------------------------------------
// Pass 2: scatter-add 48-dim features into compact mean buffer.
// ---------------------------------------------------------------------------
__global__ __launch_bounds__(256) void k_scatterM(
    const float* __restrict__ feats, const int* __restrict__ ptvox,
    const int* __restrict__ invmap, float* __restrict__ compactM)
{
    int idx = blockIdx.x * 256 + threadIdx.x;     // (pn)*CG + k, < NPTS*CG
    int k  = idx % CG;
    int pn = idx / CG;
    int bv = ptvox[pn];
    if (bv < 0) return;
    int slot = invmap[bv] - 1;
    atomicAdd(&compactM[(size_t)slot * CG + k], feats[idx]);
}

// ---------------------------------------------------------------------------
// Pass 3: project occ_volume 256 -> 48 channels: P[bt][vox][g].
// 256 thr, 1 vox/thread, UNROLL=8 load-ahead pipeline. 12 waves/CU.
// ---------------------------------------------------------------------------
__global__ __launch_bounds__(256) void k_volproj(
    const float* __restrict__ occ, const float* __restrict__ Wo2g,
    float* __restrict__ P)
{
    __shared__ float Wl[CO * CG];                 // 48 KB
    for (int j = threadIdx.x; j < CO * CG; j += 256) Wl[j] = Wo2g[j];
    __syncthreads();
    int v  = blockIdx.x * 256 + threadIdx.x;
    int bt = blockIdx.y;
    if (v >= NVOX) return;
    const float* base = occ + (size_t)bt * CO * NVOX + v;
    float acc[CG];
#pragma unroll
    for (int g = 0; g < CG; ++g) acc[g] = 0.f;
    constexpr int UN = 8;
    for (int c0 = 0; c0 < CO; c0 += UN) {
        float buf[UN];
#pragma unroll
        for (int u = 0; u < UN; ++u)
            buf[u] = base[(size_t)(c0 + u) * NVOX];
#pragma unroll
        for (int u = 0; u < UN; ++u) {
            float ov = buf[u];
            const float4* w4 = reinterpret_cast<const float4*>(&Wl[(c0 + u) * CG]);
#pragma unroll
            for (int q = 0; q < CG / 4; ++q) {
                float4 wv = w4[q];
                acc[4 * q + 0] = fmaf(ov, wv.x, acc[4 * q + 0]);
                acc[4 * q + 1] = fmaf(ov, wv.y, acc[4 * q + 1]);
                acc[4 * q + 2] = fmaf(ov, wv.z, acc[4 * q + 2]);
                acc[4 * q + 3] = fmaf(ov, wv.w, acc[4 * q + 3]);
            }
        }
    }
    float* o = P + ((size_t)bt * NVOX + v) * CG;
#pragma unroll
    for (int g = 0; g < CG; ++g) o[g] = acc[g];
}

// ---------------------------------------------------------------------------
// Pass 4: trilinear gather from P + bias -> occ_to_gs output.
// ---------------------------------------------------------------------------
__global__ __launch_bounds__(256) void k_gather(
    const float* __restrict__ pts, const float* __restrict__ P,
    const float* __restrict__ bo2g, float* __restrict__ out1)
{
    int idx = blockIdx.x * 256 + threadIdx.x;     // (pn)*CG + g
    int g  = idx % CG;
    int pn = idx / CG;
    int bt = pn / NPT;
    float x = pts[pn * 3 + 0];
    float y = pts[pn * 3 + 1];
    float z = pts[pn * 3 + 2];
    float gx = (x - GMX) / 80.0f * 2.0f - 1.0f;
    float gy = (y - GMY) / 80.0f * 2.0f - 1.0f;
    float gz = (z - GMZ) / 8.0f  * 2.0f - 1.0f;
    float px = ((gx + 1.0f) * (float)NXc - 1.0f) * 0.5f;
    float py = ((gy + 1.0f) * (float)NYc - 1.0f) * 0.5f;
    float pz = ((gz + 1.0f) * (float)NZc - 1.0f) * 0.5f;
    float fx = floorf(px), fy = floorf(py), fz = floorf(pz);
    float rx = px - fx, ry = py - fy, rz = pz - fz;
    int x0 = (int)fx, y0 = (int)fy, z0 = (int)fz;
    float acc = bo2g[g];
    const float* Pb = P + (size_t)bt * NVOX * CG;
#pragma unroll
    for (int dz = 0; dz <= 1; ++dz) {
        int zi = z0 + dz;
        if (zi < 0 || zi >= NZc) continue;
        float wz = dz ? rz : 1.0f - rz;
#pragma unroll
        for (int dy = 0; dy <= 1; ++dy) {
            int yi = y0 + dy;
            if (yi < 0 || yi >= NYc) continue;
            float wy = dy ? ry : 1.0f - ry;
#pragma unroll
            for (int dx = 0; dx <= 1; ++dx) {
                int xi = x0 + dx;
                if (xi < 0 || xi >= NXc) continue;
                float wx = dx ? rx : 1.0f - rx;
                float w = (wx * wy) * wz;
                int lin = zi * (NYc * NXc) + yi * NXc + xi;
                acc = fmaf(w, Pb[(size_t)lin * CG + g], acc);
            }
        }
    }
    out1[idx] = acc;
}

// ---------------------------------------------------------------------------
// Pass 5: sparse GEMM — compact256[slot][256] = mean[slot][48] @ Wg2o + b.
// ---------------------------------------------------------------------------
__global__ __launch_bounds__(256) void k_gemm(
    const float* __restrict__ compactM, const float* __restrict__ cnt,
    const int* __restrict__ list, const int* __restrict__ noccp,
    const float* __restrict__ Wg2o, const float* __restrict__ bg2o,
    float* __restrict__ compact256)
{
    int nocc = *noccp;
    int s0 = blockIdx.x * 32;
    if (s0 >= nocc) return;                      // uniform per block
    __shared__ float Wl[CG * CO];                // 48 KB, [k][c]
    __shared__ float Ml[32 * CG];                // 6 KB means
    for (int j = threadIdx.x; j < CG * CO; j += 256) Wl[j] = Wg2o[j];
    for (int j = threadIdx.x; j < 32 * CG; j += 256) {
        int v = j / CG, k = j - v * CG;
        int slot = s0 + v;
        float m = 0.f;
        if (slot < nocc) {
            int btvox = list[slot];
            m = compactM[(size_t)slot * CG + k] / cnt[btvox];
        }
        Ml[j] = m;
    }
    __syncthreads();
    int wid = threadIdx.x >> 6, l = threadIdx.x & 63;
    int vb = wid * 8;
    float4 bias = *reinterpret_cast<const float4*>(&bg2o[4 * l]);
    float acc[8][4];
#pragma unroll
    for (int v = 0; v < 8; ++v) {
        acc[v][0] = bias.x; acc[v][1] = bias.y; acc[v][2] = bias.z; acc[v][3] = bias.w;
    }
    for (int k = 0; k < CG; k += 4) {
        float4 w0 = *reinterpret_cast<const float4*>(&Wl[(k + 0) * CO + 4 * l]);
        float4 w1 = *reinterpret_cast<const float4*>(&Wl[(k + 1) * CO + 4 * l]);
        float4 w2 = *reinterpret_cast<const float4*>(&Wl[(k + 2) * CO + 4 * l]);
        float4 w3 = *reinterpret_cast<const float4*>(&Wl[(k + 3) * CO + 4 * l]);
#pragma unroll
        for (int v = 0; v < 8; ++v) {
            float4 m4 = *reinterpret_cast<const float4*>(&Ml[(vb + v) * CG + k]);
            acc[v][0] = fmaf(m4.x, w0.x, acc[v][0]);
            acc[v][1] = fmaf(m4.x, w0.y, acc[v][1]);
            acc[v][2] = fmaf(m4.x, w0.z, acc[v][2]);
            acc[v][3] = fmaf(m4.x, w0.w, acc[v][3]);
            acc[v][0] = fmaf(m4.y, w1.x, acc[v][0]);
            acc[v][1] = fmaf(m4.y, w1.y, acc[v][1]);
            acc[v][2] = fmaf(m4.y, w1.z, acc[v][2]);
            acc[v][3] = fmaf(m4.y, w1.w, acc[v][3]);
            acc[v][0] = fmaf(m4.z, w2.x, acc[v][0]);
            acc[v][1] = fmaf(m4.z, w2.y, acc[v][1]);
            acc[v][2] = fmaf(m4.z, w2.z, acc[v][2]);
            acc[v][3] = fmaf(m4.z, w2.w, acc[v][3]);
            acc[v][0] = fmaf(m4.w, w3.x, acc[v][0]);
            acc[v][1] = fmaf(m4.w, w3.y, acc[v][1]);
            acc[v][2] = fmaf(m4.w, w3.z, acc[v][2]);
            acc[v][3] = fmaf(m4.w, w3.w, acc[v][3]);
        }
    }
#pragma unroll
    for (int v = 0; v < 8; ++v) {
        int slot = s0 + vb + v;
        if (slot < nocc) {
            float4 r; r.x = acc[v][0]; r.y = acc[v][1]; r.z = acc[v][2]; r.w = acc[v][3];
            *reinterpret_cast<float4*>(&compact256[(size_t)slot * CO + 4 * l]) = r;
        }
    }
}

// ---------------------------------------------------------------------------
// Pass 6: dense writer. Thread -> 4 consecutive vox; loop 32 channels.
// ---------------------------------------------------------------------------
__global__ __launch_bounds__(256) void k_writer(
    const int* __restrict__ invmap, const float* __restrict__ compact256,
    float* __restrict__ out0)
{
    int bt = blockIdx.z;
    int c0 = blockIdx.y * 32;
    int v0 = blockIdx.x * 1024 + threadIdx.x * 4;
    if (v0 >= NVOX) return;
    int4 sp = *reinterpret_cast<const int4*>(&invmap[bt * NVOX + v0]);
    const float* r0 = compact256 + (size_t)(sp.x - 1) * CO;
    const float* r1 = compact256 + (size_t)(sp.y - 1) * CO;
    const float* r2 = compact256 + (size_t)(sp.z - 1) * CO;
    const float* r3 = compact256 + (size_t)(sp.w - 1) * CO;
    float* ob = out0 + (size_t)bt * CO * NVOX + (size_t)c0 * NVOX + v0;
#pragma unroll 4
    for (int ci = 0; ci < 32; ++ci) {
        int c = c0 + ci;
        v4f val;
        val.x = sp.x ? r0[c] : 0.f;
        val.y = sp.y ? r1[c] : 0.f;
        val.z = sp.z ? r2[c] : 0.f;
        val.w = sp.w ? r3[c] : 0.f;
        __builtin_nontemporal_store(val, reinterpret_cast<v4f*>(ob + (size_t)ci * NVOX));
    }
}

// ---------------------------------------------------------------------------
extern "C" void kernel_launch(void* const* d_in, const int* in_sizes, int n_in,
                              void* d_out, int out_size, void* d_ws, size_t ws_size,
                              hipStream_t stream)
{
    const float* centers = (const float*)d_in[0];
    const float* feats   = (const float*)d_in[1];
    const float* occ     = (const float*)d_in[2];
    const float* Wg2o    = (const float*)d_in[3];
    const float* bg2o    = (const float*)d_in[4];
    const float* Wo2g    = (const float*)d_in[5];
    const float* bo2g    = (const float*)d_in[6];

    float* out  = (float*)d_out;
    float* out0 = out;                                   // [BT][CO][NVOX]
    float* out1 = out + (size_t)BT * CO * NVOX;          // [BT][NPT][CG]
    // P in tail of out0: written by volproj, read by gather, overwritten by writer.
    float* P    = out0 + (size_t)BT * CO * NVOX - (size_t)BT * NVOX * CG;

    // ws layout (bytes):
    char* w = (char*)d_ws;
    float* cnt       = (float*)w;                 w += (size_t)BT * NVOX * 4;       // 800000
    int*   nocc      = (int*)w;                   w += 256;
    int*   invmap    = (int*)w;                   w += (size_t)BT * NVOX * 4;       // 800000
    int*   ptvox     = (int*)w;                   w += (size_t)NPTS * 4;            // 135168
    int*   list      = (int*)w;                   w += (size_t)MAXS * 4;            // 135168
    float* compactM  = (float*)w;                 w += (size_t)MAXS * CG * 4;       // 6488064
    float* compact256= (float*)w;                 // MAXS*CO*4 = 34603008
    size_t zbytes = (size_t)BT * NVOX * 4 + 256 + (size_t)BT * NVOX * 4
                  + (size_t)NPTS * 4 + (size_t)MAXS * 4 + (size_t)MAXS * CG * 4;
    (void)hipMemsetAsync(d_ws, 0, zbytes, stream);      // ~8.4 MB

    k_count<<<NPTS / 256, 256, 0, stream>>>(centers, cnt, nocc, invmap, ptvox);
    k_mklist<<<(BT * NVOX + 255) / 256, 256, 0, stream>>>(invmap, list);
    k_scatterM<<<NPTS * CG / 256, 256, 0, stream>>>(feats, ptvox, invmap, compactM);
    k_volproj<<<dim3((NVOX + 255) / 256, BT), 256, 0, stream>>>(occ, Wo2g, P);
    k_gather<<<NPTS * CG / 256, 256, 0, stream>>>(centers, P, bo2g, out1);
    k_gemm<<<(MAXS + 31) / 32, 256, 0, stream>>>(compactM, cnt, list, nocc, Wg2o, bg2o, compact256);
    k_writer<<<dim3((NVOX + 1023) / 1024, 8, BT), 256, 0, stream>>>(invmap, compact256, out0);
}

// Round 5
// 225.343 us; speedup vs baseline: 2.1251x; 1.0520x over previous
//
#include <hip/hip_runtime.h>

typedef float v4f __attribute__((ext_vector_type(4)));

// Problem constants (match reference)
constexpr int NXc = 100, NYc = 100, NZc = 10;
constexpr int NVOX = NZc * NYc * NXc;      // 100000
constexpr int CO = 256, CG = 48;
constexpr int BT = 2;
constexpr int NPT = 6 * 32 * 88;           // 16896 points per bt
constexpr int NPTS = BT * NPT;             // 33792
constexpr int MAXS = NPTS;                 // max occupied voxels
constexpr float GMX = -40.0f, GMY = -40.0f, GMZ = -2.0f;
constexpr float VOXEL = 0.8f;

// ---------------------------------------------------------------------------
// Pass 1: per point -> voxel; count + assign compact slots.
// ---------------------------------------------------------------------------
__global__ __launch_bounds__(256) void k_count(
    const float* __restrict__ pts, float* __restrict__ cnt,
    int* __restrict__ nocc, int* __restrict__ invmap, int* __restrict__ ptvox)
{
    int pn = blockIdx.x * 256 + threadIdx.x;      // < NPTS (exact grid)
    float x = pts[pn * 3 + 0];
    float y = pts[pn * 3 + 1];
    float z = pts[pn * 3 + 2];
    int ix = (int)floorf((x - GMX) / VOXEL);
    int iy = (int)floorf((y - GMY) / VOXEL);
    int iz = (int)floorf((z - GMZ) / VOXEL);
    bool valid = (ix >= 0 && ix < NXc && iy >= 0 && iy < NYc && iz >= 0 && iz < NZc);
    if (!valid) { ptvox[pn] = -1; return; }
    int bt = pn / NPT;
    int btvox = bt * NVOX + iz * (NYc * NXc) + iy * NXc + ix;
    ptvox[pn] = btvox;
    float old = atomicAdd(&cnt[btvox], 1.0f);
    if (old == 0.0f) {
        int s = atomicAdd(nocc, 1);
        invmap[btvox] = s + 1;                    // 0 = empty
    }
}

// list[slot] = btvox needed by gemm for cnt lookup.
__global__ __launch_bounds__(256) void k_mklist(
    const int* __restrict__ invmap, int* __restrict__ list)
{
    int v = blockIdx.x * 256 + threadIdx.x;       // < BT*NVOX
    if (v >= BT * NVOX) return;
    int sp = invmap[v];
    if (sp) list[sp - 1] = v;
}

// ---------------------------------------------------------------------------
// Pass 2: scatter-add 48-dim features into compact mean buffer.
// ---------------------------------------------------------------------------
__global__ __launch_bounds__(256) void k_scatterM(
    const float* __restrict__ feats, const int* __restrict__ ptvox,
    const int* __restrict__ invmap, float* __restrict__ compactM)
{
    int idx = blockIdx.x * 256 + threadIdx.x;     // (pn)*CG + k, < NPTS*CG
    int k  = idx % CG;
    int pn = idx / CG;
    int bv = ptvox[pn];
    if (bv < 0) return;
    int slot = invmap[bv] - 1;
    atomicAdd(&compactM[(size_t)slot * CG + k], feats[idx]);
}

// ---------------------------------------------------------------------------
// Pass 3: project occ_volume 256 -> 48 channels: P[bt][vox][g].
// No LDS: W rows are wave-uniform -> scalar (s_load) operands. Double-
// buffered global loads keep 8 x 256B in flight under the FMA block.
// ---------------------------------------------------------------------------
__global__ __launch_bounds__(256) void k_volproj(
    const float* __restrict__ occ, const float* __restrict__ Wo2g,
    float* __restrict__ P)
{
    int v  = blockIdx.x * 256 + threadIdx.x;
    int bt = blockIdx.y;
    if (v >= NVOX) return;
    const float* base = occ + (size_t)bt * CO * NVOX + v;
    float acc[CG];
#pragma unroll
    for (int g = 0; g < CG; ++g) acc[g] = 0.f;
    constexpr int UN = 8;
    float buf[UN];
#pragma unroll
    for (int u = 0; u < UN; ++u) buf[u] = base[(size_t)u * NVOX];
    for (int c0 = 0; c0 < CO; c0 += UN) {
        float cur[UN];
#pragma unroll
        for (int u = 0; u < UN; ++u) cur[u] = buf[u];
        if (c0 + UN < CO) {
#pragma unroll
            for (int u = 0; u < UN; ++u)
                buf[u] = base[(size_t)(c0 + UN + u) * NVOX];
        }
#pragma unroll
        for (int u = 0; u < UN; ++u) {
            float ov = cur[u];
            const float* w = &Wo2g[(c0 + u) * CG];   // uniform -> SGPR
#pragma unroll
            for (int g = 0; g < CG; ++g)
                acc[g] = fmaf(ov, w[g], acc[g]);
        }
    }
    float* o = P + ((size_t)bt * NVOX + v) * CG;
#pragma unroll
    for (int g = 0; g < CG; ++g) o[g] = acc[g];
}

// ---------------------------------------------------------------------------
// Pass 4: trilinear gather from P + bias -> occ_to_gs output.
// ---------------------------------------------------------------------------
__global__ __launch_bounds__(256) void k_gather(
    const float* __restrict__ pts, const float* __restrict__ P,
    const float* __restrict__ bo2g, float* __restrict__ out1)
{
    int idx = blockIdx.x * 256 + threadIdx.x;     // (pn)*CG + g
    int g  = idx % CG;
    int pn = idx / CG;
    int bt = pn / NPT;
    float x = pts[pn * 3 + 0];
    float y = pts[pn * 3 + 1];
    float z = pts[pn * 3 + 2];
    float gx = (x - GMX) / 80.0f * 2.0f - 1.0f;
    float gy = (y - GMY) / 80.0f * 2.0f - 1.0f;
    float gz = (z - GMZ) / 8.0f  * 2.0f - 1.0f;
    float px = ((gx + 1.0f) * (float)NXc - 1.0f) * 0.5f;
    float py = ((gy + 1.0f) * (float)NYc - 1.0f) * 0.5f;
    float pz = ((gz + 1.0f) * (float)NZc - 1.0f) * 0.5f;
    float fx = floorf(px), fy = floorf(py), fz = floorf(pz);
    float rx = px - fx, ry = py - fy, rz = pz - fz;
    int x0 = (int)fx, y0 = (int)fy, z0 = (int)fz;
    float acc = bo2g[g];
    const float* Pb = P + (size_t)bt * NVOX * CG;
#pragma unroll
    for (int dz = 0; dz <= 1; ++dz) {
        int zi = z0 + dz;
        if (zi < 0 || zi >= NZc) continue;
        float wz = dz ? rz : 1.0f - rz;
#pragma unroll
        for (int dy = 0; dy <= 1; ++dy) {
            int yi = y0 + dy;
            if (yi < 0 || yi >= NYc) continue;
            float wy = dy ? ry : 1.0f - ry;
#pragma unroll
            for (int dx = 0; dx <= 1; ++dx) {
                int xi = x0 + dx;
                if (xi < 0 || xi >= NXc) continue;
                float wx = dx ? rx : 1.0f - rx;
                float w = (wx * wy) * wz;
                int lin = zi * (NYc * NXc) + yi * NXc + xi;
                acc = fmaf(w, Pb[(size_t)lin * CG + g], acc);
            }
        }
    }
    out1[idx] = acc;
}

// ---------------------------------------------------------------------------
// Pass 5: sparse GEMM — compact256[slot][256] = mean[slot][48] @ Wg2o + b.
// ---------------------------------------------------------------------------
__global__ __launch_bounds__(256) void k_gemm(
    const float* __restrict__ compactM, const float* __restrict__ cnt,
    const int* __restrict__ list, const int* __restrict__ noccp,
    const float* __restrict__ Wg2o, const float* __restrict__ bg2o,
    float* __restrict__ compact256)
{
    int nocc = *noccp;
    int s0 = blockIdx.x * 32;
    if (s0 >= nocc) return;                      // uniform per block
    __shared__ float Wl[CG * CO];                // 48 KB, [k][c]
    __shared__ float Ml[32 * CG];                // 6 KB means
    for (int j = threadIdx.x; j < CG * CO; j += 256) Wl[j] = Wg2o[j];
    for (int j = threadIdx.x; j < 32 * CG; j += 256) {
        int v = j / CG, k = j - v * CG;
        int slot = s0 + v;
        float m = 0.f;
        if (slot < nocc) {
            int btvox = list[slot];
            m = compactM[(size_t)slot * CG + k] / cnt[btvox];
        }
        Ml[j] = m;
    }
    __syncthreads();
    int wid = threadIdx.x >> 6, l = threadIdx.x & 63;
    int vb = wid * 8;
    float4 bias = *reinterpret_cast<const float4*>(&bg2o[4 * l]);
    float acc[8][4];
#pragma unroll
    for (int v = 0; v < 8; ++v) {
        acc[v][0] = bias.x; acc[v][1] = bias.y; acc[v][2] = bias.z; acc[v][3] = bias.w;
    }
    for (int k = 0; k < CG; k += 4) {
        float4 w0 = *reinterpret_cast<const float4*>(&Wl[(k + 0) * CO + 4 * l]);
        float4 w1 = *reinterpret_cast<const float4*>(&Wl[(k + 1) * CO + 4 * l]);
        float4 w2 = *reinterpret_cast<const float4*>(&Wl[(k + 2) * CO + 4 * l]);
        float4 w3 = *reinterpret_cast<const float4*>(&Wl[(k + 3) * CO + 4 * l]);
#pragma unroll
        for (int v = 0; v < 8; ++v) {
            float4 m4 = *reinterpret_cast<const float4*>(&Ml[(vb + v) * CG + k]);
            acc[v][0] = fmaf(m4.x, w0.x, acc[v][0]);
            acc[v][1] = fmaf(m4.x, w0.y, acc[v][1]);
            acc[v][2] = fmaf(m4.x, w0.z, acc[v][2]);
            acc[v][3] = fmaf(m4.x, w0.w, acc[v][3]);
            acc[v][0] = fmaf(m4.y, w1.x, acc[v][0]);
            acc[v][1] = fmaf(m4.y, w1.y, acc[v][1]);
            acc[v][2] = fmaf(m4.y, w1.z, acc[v][2]);
            acc[v][3] = fmaf(m4.y, w1.w, acc[v][3]);
            acc[v][0] = fmaf(m4.z, w2.x, acc[v][0]);
            acc[v][1] = fmaf(m4.z, w2.y, acc[v][1]);
            acc[v][2] = fmaf(m4.z, w2.z, acc[v][2]);
            acc[v][3] = fmaf(m4.z, w2.w, acc[v][3]);
            acc[v][0] = fmaf(m4.w, w3.x, acc[v][0]);
            acc[v][1] = fmaf(m4.w, w3.y, acc[v][1]);
            acc[v][2] = fmaf(m4.w, w3.z, acc[v][2]);
            acc[v][3] = fmaf(m4.w, w3.w, acc[v][3]);
        }
    }
#pragma unroll
    for (int v = 0; v < 8; ++v) {
        int slot = s0 + vb + v;
        if (slot < nocc) {
            float4 r; r.x = acc[v][0]; r.y = acc[v][1]; r.z = acc[v][2]; r.w = acc[v][3];
            *reinterpret_cast<float4*>(&compact256[(size_t)slot * CO + 4 * l]) = r;
        }
    }
}

// ---------------------------------------------------------------------------
// Pass 6: dense writer. Thread -> 4 consecutive vox; loop 32 channels.
// ---------------------------------------------------------------------------
__global__ __launch_bounds__(256) void k_writer(
    const int* __restrict__ invmap, const float* __restrict__ compact256,
    float* __restrict__ out0)
{
    int bt = blockIdx.z;
    int c0 = blockIdx.y * 32;
    int v0 = blockIdx.x * 1024 + threadIdx.x * 4;
    if (v0 >= NVOX) return;
    int4 sp = *reinterpret_cast<const int4*>(&invmap[bt * NVOX + v0]);
    const float* r0 = compact256 + (size_t)(sp.x - 1) * CO;
    const float* r1 = compact256 + (size_t)(sp.y - 1) * CO;
    const float* r2 = compact256 + (size_t)(sp.z - 1) * CO;
    const float* r3 = compact256 + (size_t)(sp.w - 1) * CO;
    float* ob = out0 + (size_t)bt * CO * NVOX + (size_t)c0 * NVOX + v0;
#pragma unroll 4
    for (int ci = 0; ci < 32; ++ci) {
        int c = c0 + ci;
        v4f val;
        val.x = sp.x ? r0[c] : 0.f;
        val.y = sp.y ? r1[c] : 0.f;
        val.z = sp.z ? r2[c] : 0.f;
        val.w = sp.w ? r3[c] : 0.f;
        __builtin_nontemporal_store(val, reinterpret_cast<v4f*>(ob + (size_t)ci * NVOX));
    }
}

// ---------------------------------------------------------------------------
extern "C" void kernel_launch(void* const* d_in, const int* in_sizes, int n_in,
                              void* d_out, int out_size, void* d_ws, size_t ws_size,
                              hipStream_t stream)
{
    const float* centers = (const float*)d_in[0];
    const float* feats   = (const float*)d_in[1];
    const float* occ     = (const float*)d_in[2];
    const float* Wg2o    = (const float*)d_in[3];
    const float* bg2o    = (const float*)d_in[4];
    const float* Wo2g    = (const float*)d_in[5];
    const float* bo2g    = (const float*)d_in[6];

    float* out  = (float*)d_out;
    float* out0 = out;                                   // [BT][CO][NVOX]
    float* out1 = out + (size_t)BT * CO * NVOX;          // [BT][NPT][CG]
    // P in tail of out0: written by volproj, read by gather, overwritten by writer.
    float* P    = out0 + (size_t)BT * CO * NVOX - (size_t)BT * NVOX * CG;

    // ws layout (bytes):
    char* w = (char*)d_ws;
    float* cnt       = (float*)w;                 w += (size_t)BT * NVOX * 4;       // 800000
    int*   nocc      = (int*)w;                   w += 256;
    int*   invmap    = (int*)w;                   w += (size_t)BT * NVOX * 4;       // 800000
    int*   ptvox     = (int*)w;                   w += (size_t)NPTS * 4;            // 135168
    int*   list      = (int*)w;                   w += (size_t)MAXS * 4;            // 135168
    float* compactM  = (float*)w;                 w += (size_t)MAXS * CG * 4;       // 6488064
    float* compact256= (float*)w;                 // MAXS*CO*4 = 34603008
    size_t zbytes = (size_t)BT * NVOX * 4 + 256 + (size_t)BT * NVOX * 4
                  + (size_t)NPTS * 4 + (size_t)MAXS * 4 + (size_t)MAXS * CG * 4;
    (void)hipMemsetAsync(d_ws, 0, zbytes, stream);      // ~8.4 MB

    k_count<<<NPTS / 256, 256, 0, stream>>>(centers, cnt, nocc, invmap, ptvox);
    k_mklist<<<(BT * NVOX + 255) / 256, 256, 0, stream>>>(invmap, list);
    k_scatterM<<<NPTS * CG / 256, 256, 0, stream>>>(feats, ptvox, invmap, compactM);
    k_volproj<<<dim3((NVOX + 255) / 256, BT), 256, 0, stream>>>(occ, Wo2g, P);
    k_gather<<<NPTS * CG / 256, 256, 0, stream>>>(centers, P, bo2g, out1);
    k_gemm<<<(MAXS + 31) / 32, 256, 0, stream>>>(compactM, cnt, list, nocc, Wg2o, bg2o, compact256);
    k_writer<<<dim3((NVOX + 1023) / 1024, 8, BT), 256, 0, stream>>>(invmap, compact256, out0);
}

// Round 6
// 185.174 us; speedup vs baseline: 2.5861x; 1.2169x over previous
//
#include <hip/hip_runtime.h>
#include <hip/hip_bf16.h>

typedef float v4f __attribute__((ext_vector_type(4)));
typedef short bfrag8 __attribute__((ext_vector_type(8)));

// Problem constants (match reference)
constexpr int NXc = 100, NYc = 100, NZc = 10;
constexpr int NVOX = NZc * NYc * NXc;      // 100000
constexpr int CO = 256, CG = 48;
constexpr int BT = 2;
constexpr int NPT = 6 * 32 * 88;           // 16896 points per bt
constexpr int NPTS = BT * NPT;             // 33792
constexpr int MAXS = NPTS;                 // max occupied voxels
constexpr int NTILES = NVOX / 16;          // 6250 vox-tiles per bt
constexpr float GMX = -40.0f, GMY = -40.0f, GMZ = -2.0f;
constexpr float VOXEL = 0.8f;

static __device__ __forceinline__ short f2bf(float f) {
    __hip_bfloat16 h = __float2bfloat16(f);
    return __builtin_bit_cast(short, h);
}

// ---------------------------------------------------------------------------
// Pass 1: per point -> voxel; count + assign compact slots.
// ---------------------------------------------------------------------------
__global__ __launch_bounds__(256) void k_count(
    const float* __restrict__ pts, float* __restrict__ cnt,
    int* __restrict__ nocc, int* __restrict__ invmap, int* __restrict__ ptvox)
{
    int pn = blockIdx.x * 256 + threadIdx.x;      // < NPTS (exact grid)
    float x = pts[pn * 3 + 0];
    float y = pts[pn * 3 + 1];
    float z = pts[pn * 3 + 2];
    int ix = (int)floorf((x - GMX) / VOXEL);
    int iy = (int)floorf((y - GMY) / VOXEL);
    int iz = (int)floorf((z - GMZ) / VOXEL);
    bool valid = (ix >= 0 && ix < NXc && iy >= 0 && iy < NYc && iz >= 0 && iz < NZc);
    if (!valid) { ptvox[pn] = -1; return; }
    int bt = pn / NPT;
    int btvox = bt * NVOX + iz * (NYc * NXc) + iy * NXc + ix;
    ptvox[pn] = btvox;
    float old = atomicAdd(&cnt[btvox], 1.0f);
    if (old == 0.0f) {
        int s = atomicAdd(nocc, 1);
        invmap[btvox] = s + 1;                    // 0 = empty
    }
}

// list[slot] = btvox needed by gemm for cnt lookup.
__global__ __launch_bounds__(256) void k_mklist(
    const int* __restrict__ invmap, int* __restrict__ list)
{
    int v = blockIdx.x * 256 + threadIdx.x;       // < BT*NVOX
    if (v >= BT * NVOX) return;
    int sp = invmap[v];
    if (sp) list[sp - 1] = v;
}

// ---------------------------------------------------------------------------
// Pass 2: scatter-add 48-dim features into compact mean buffer.
// ---------------------------------------------------------------------------
__global__ __launch_bounds__(256) void k_scatterM(
    const float* __restrict__ feats, const int* __restrict__ ptvox,
    const int* __restrict__ invmap, float* __restrict__ compactM)
{
    int idx = blockIdx.x * 256 + threadIdx.x;     // (pn)*CG + k, < NPTS*CG
    int k  = idx % CG;
    int pn = idx / CG;
    int bv = ptvox[pn];
    if (bv < 0) return;
    int slot = invmap[bv] - 1;
    atomicAdd(&compactM[(size_t)slot * CG + k], feats[idx]);
}

// ---------------------------------------------------------------------------
// Pass 3a: pack Wo2g^T into bf16 MFMA A-fragments.
// Fragment (s,gt): lane l slot j holds W[k][g], k = s*32 + (l>>4)*8 + j,
// g = gt*16 + (l&15).  wp[((s*3+gt)*64 + l)*8 + j].
// ---------------------------------------------------------------------------
__global__ __launch_bounds__(256) void k_packW(
    const float* __restrict__ Wo2g, short* __restrict__ wp)
{
    for (int e = threadIdx.x; e < 8 * 3 * 64 * 8; e += 256) {
        int j  = e & 7;
        int l  = (e >> 3) & 63;
        int ft = e >> 9;                          // s*3 + gt
        int s  = ft / 3, gt = ft - 3 * s;
        int k  = s * 32 + (l >> 4) * 8 + j;
        int g  = gt * 16 + (l & 15);
        wp[e] = f2bf(Wo2g[k * CG + g]);
    }
}

// ---------------------------------------------------------------------------
// Pass 3b: P[bt][vox][48] = occ[bt][:,vox]^T @ Wo2g via bf16 MFMA.
// One wave per 16-vox tile: D[48 g][16 vox] = Wt[48x256] * X[256x16].
// A/B share the k-map k=(l>>4)*8+j (any shared bijection is correct).
// C/D layout (m89): col = lane&15 (vox), row = (lane>>4)*4+reg (g).
// ---------------------------------------------------------------------------
__global__ __launch_bounds__(256) void k_volproj(
    const float* __restrict__ occ, const short* __restrict__ wp,
    float* __restrict__ P)
{
    int gwid = (blockIdx.x * 256 + threadIdx.x) >> 6;
    int l = threadIdx.x & 63;
    int q = l >> 4, r = l & 15;
    int nwaves = gridDim.x * 4;
    const bfrag8* wf = reinterpret_cast<const bfrag8*>(wp);
    for (int tile = gwid; tile < BT * NTILES; tile += nwaves) {
        int bt = tile / NTILES;
        int vox0 = (tile - bt * NTILES) * 16;
        const float* base = occ + (size_t)bt * CO * NVOX + vox0 + r;
        v4f acc0 = {0.f, 0.f, 0.f, 0.f};
        v4f acc1 = {0.f, 0.f, 0.f, 0.f};
        v4f acc2 = {0.f, 0.f, 0.f, 0.f};
#pragma unroll
        for (int s = 0; s < 8; ++s) {
            float b[8];
#pragma unroll
            for (int j = 0; j < 8; ++j)
                b[j] = base[(size_t)(s * 32 + q * 8 + j) * NVOX];
            bfrag8 bf;
#pragma unroll
            for (int j = 0; j < 8; ++j) bf[j] = f2bf(b[j]);
            bfrag8 a0 = wf[(s * 3 + 0) * 64 + l];
            bfrag8 a1 = wf[(s * 3 + 1) * 64 + l];
            bfrag8 a2 = wf[(s * 3 + 2) * 64 + l];
            acc0 = __builtin_amdgcn_mfma_f32_16x16x32_bf16(a0, bf, acc0, 0, 0, 0);
            acc1 = __builtin_amdgcn_mfma_f32_16x16x32_bf16(a1, bf, acc1, 0, 0, 0);
            acc2 = __builtin_amdgcn_mfma_f32_16x16x32_bf16(a2, bf, acc2, 0, 0, 0);
        }
        float* o = P + ((size_t)bt * NVOX + vox0 + r) * CG + q * 4;
        *reinterpret_cast<v4f*>(o)      = acc0;   // g = q*4+reg
        *reinterpret_cast<v4f*>(o + 16) = acc1;   // g = 16 + q*4+reg
        *reinterpret_cast<v4f*>(o + 32) = acc2;   // g = 32 + q*4+reg
    }
}

// ---------------------------------------------------------------------------
// Pass 4: trilinear gather from P + bias -> occ_to_gs output.
// ---------------------------------------------------------------------------
__global__ __launch_bounds__(256) void k_gather(
    const float* __restrict__ pts, const float* __restrict__ P,
    const float* __restrict__ bo2g, float* __restrict__ out1)
{
    int idx = blockIdx.x * 256 + threadIdx.x;     // (pn)*CG + g
    int g  = idx % CG;
    int pn = idx / CG;
    int bt = pn / NPT;
    float x = pts[pn * 3 + 0];
    float y = pts[pn * 3 + 1];
    float z = pts[pn * 3 + 2];
    float gx = (x - GMX) / 80.0f * 2.0f - 1.0f;
    float gy = (y - GMY) / 80.0f * 2.0f - 1.0f;
    float gz = (z - GMZ) / 8.0f  * 2.0f - 1.0f;
    float px = ((gx + 1.0f) * (float)NXc - 1.0f) * 0.5f;
    float py = ((gy + 1.0f) * (float)NYc - 1.0f) * 0.5f;
    float pz = ((gz + 1.0f) * (float)NZc - 1.0f) * 0.5f;
    float fx = floorf(px), fy = floorf(py), fz = floorf(pz);
    float rx = px - fx, ry = py - fy, rz = pz - fz;
    int x0 = (int)fx, y0 = (int)fy, z0 = (int)fz;
    float acc = bo2g[g];
    const float* Pb = P + (size_t)bt * NVOX * CG;
#pragma unroll
    for (int dz = 0; dz <= 1; ++dz) {
        int zi = z0 + dz;
        if (zi < 0 || zi >= NZc) continue;
        float wz = dz ? rz : 1.0f - rz;
#pragma unroll
        for (int dy = 0; dy <= 1; ++dy) {
            int yi = y0 + dy;
            if (yi < 0 || yi >= NYc) continue;
            float wy = dy ? ry : 1.0f - ry;
#pragma unroll
            for (int dx = 0; dx <= 1; ++dx) {
                int xi = x0 + dx;
                if (xi < 0 || xi >= NXc) continue;
                float wx = dx ? rx : 1.0f - rx;
                float w = (wx * wy) * wz;
                int lin = zi * (NYc * NXc) + yi * NXc + xi;
                acc = fmaf(w, Pb[(size_t)lin * CG + g], acc);
            }
        }
    }
    out1[idx] = acc;
}

// ---------------------------------------------------------------------------
// Pass 5: sparse GEMM — compact256[slot][256] = mean[slot][48] @ Wg2o + b.
// ---------------------------------------------------------------------------
__global__ __launch_bounds__(256) void k_gemm(
    const float* __restrict__ compactM, const float* __restrict__ cnt,
    const int* __restrict__ list, const int* __restrict__ noccp,
    const float* __restrict__ Wg2o, const float* __restrict__ bg2o,
    float* __restrict__ compact256)
{
    int nocc = *noccp;
    int s0 = blockIdx.x * 32;
    if (s0 >= nocc) return;                      // uniform per block
    __shared__ float Wl[CG * CO];                // 48 KB, [k][c]
    __shared__ float Ml[32 * CG];                // 6 KB means
    for (int j = threadIdx.x; j < CG * CO; j += 256) Wl[j] = Wg2o[j];
    for (int j = threadIdx.x; j < 32 * CG; j += 256) {
        int v = j / CG, k = j - v * CG;
        int slot = s0 + v;
        float m = 0.f;
        if (slot < nocc) {
            int btvox = list[slot];
            m = compactM[(size_t)slot * CG + k] / cnt[btvox];
        }
        Ml[j] = m;
    }
    __syncthreads();
    int wid = threadIdx.x >> 6, l = threadIdx.x & 63;
    int vb = wid * 8;
    float4 bias = *reinterpret_cast<const float4*>(&bg2o[4 * l]);
    float acc[8][4];
#pragma unroll
    for (int v = 0; v < 8; ++v) {
        acc[v][0] = bias.x; acc[v][1] = bias.y; acc[v][2] = bias.z; acc[v][3] = bias.w;
    }
    for (int k = 0; k < CG; k += 4) {
        float4 w0 = *reinterpret_cast<const float4*>(&Wl[(k + 0) * CO + 4 * l]);
        float4 w1 = *reinterpret_cast<const float4*>(&Wl[(k + 1) * CO + 4 * l]);
        float4 w2 = *reinterpret_cast<const float4*>(&Wl[(k + 2) * CO + 4 * l]);
        float4 w3 = *reinterpret_cast<const float4*>(&Wl[(k + 3) * CO + 4 * l]);
#pragma unroll
        for (int v = 0; v < 8; ++v) {
            float4 m4 = *reinterpret_cast<const float4*>(&Ml[(vb + v) * CG + k]);
            acc[v][0] = fmaf(m4.x, w0.x, acc[v][0]);
            acc[v][1] = fmaf(m4.x, w0.y, acc[v][1]);
            acc[v][2] = fmaf(m4.x, w0.z, acc[v][2]);
            acc[v][3] = fmaf(m4.x, w0.w, acc[v][3]);
            acc[v][0] = fmaf(m4.y, w1.x, acc[v][0]);
            acc[v][1] = fmaf(m4.y, w1.y, acc[v][1]);
            acc[v][2] = fmaf(m4.y, w1.z, acc[v][2]);
            acc[v][3] = fmaf(m4.y, w1.w, acc[v][3]);
            acc[v][0] = fmaf(m4.z, w2.x, acc[v][0]);
            acc[v][1] = fmaf(m4.z, w2.y, acc[v][1]);
            acc[v][2] = fmaf(m4.z, w2.z, acc[v][2]);
            acc[v][3] = fmaf(m4.z, w2.w, acc[v][3]);
            acc[v][0] = fmaf(m4.w, w3.x, acc[v][0]);
            acc[v][1] = fmaf(m4.w, w3.y, acc[v][1]);
            acc[v][2] = fmaf(m4.w, w3.z, acc[v][2]);
            acc[v][3] = fmaf(m4.w, w3.w, acc[v][3]);
        }
    }
#pragma unroll
    for (int v = 0; v < 8; ++v) {
        int slot = s0 + vb + v;
        if (slot < nocc) {
            float4 rr; rr.x = acc[v][0]; rr.y = acc[v][1]; rr.z = acc[v][2]; rr.w = acc[v][3];
            *reinterpret_cast<float4*>(&compact256[(size_t)slot * CO + 4 * l]) = rr;
        }
    }
}

// ---------------------------------------------------------------------------
// Pass 6: dense writer. Thread -> 4 consecutive vox; loop 32 channels.
// ---------------------------------------------------------------------------
__global__ __launch_bounds__(256) void k_writer(
    const int* __restrict__ invmap, const float* __restrict__ compact256,
    float* __restrict__ out0)
{
    int bt = blockIdx.z;
    int c0 = blockIdx.y * 32;
    int v0 = blockIdx.x * 1024 + threadIdx.x * 4;
    if (v0 >= NVOX) return;
    int4 sp = *reinterpret_cast<const int4*>(&invmap[bt * NVOX + v0]);
    const float* r0 = compact256 + (size_t)(sp.x - 1) * CO;
    const float* r1 = compact256 + (size_t)(sp.y - 1) * CO;
    const float* r2 = compact256 + (size_t)(sp.z - 1) * CO;
    const float* r3 = compact256 + (size_t)(sp.w - 1) * CO;
    float* ob = out0 + (size_t)bt * CO * NVOX + (size_t)c0 * NVOX + v0;
#pragma unroll 4
    for (int ci = 0; ci < 32; ++ci) {
        int c = c0 + ci;
        v4f val;
        val.x = sp.x ? r0[c] : 0.f;
        val.y = sp.y ? r1[c] : 0.f;
        val.z = sp.z ? r2[c] : 0.f;
        val.w = sp.w ? r3[c] : 0.f;
        __builtin_nontemporal_store(val, reinterpret_cast<v4f*>(ob + (size_t)ci * NVOX));
    }
}

// ---------------------------------------------------------------------------
extern "C" void kernel_launch(void* const* d_in, const int* in_sizes, int n_in,
                              void* d_out, int out_size, void* d_ws, size_t ws_size,
                              hipStream_t stream)
{
    const float* centers = (const float*)d_in[0];
    const float* feats   = (const float*)d_in[1];
    const float* occ     = (const float*)d_in[2];
    const float* Wg2o    = (const float*)d_in[3];
    const float* bg2o    = (const float*)d_in[4];
    const float* Wo2g    = (const float*)d_in[5];
    const float* bo2g    = (const float*)d_in[6];

    float* out  = (float*)d_out;
    float* out0 = out;                                   // [BT][CO][NVOX]
    float* out1 = out + (size_t)BT * CO * NVOX;          // [BT][NPT][CG]
    // P in tail of out0: written by volproj, read by gather, overwritten by writer.
    float* P    = out0 + (size_t)BT * CO * NVOX - (size_t)BT * NVOX * CG;
    // Packed bf16 W fragments live at the head of out1 (24 KB): written by
    // k_packW, read by k_volproj, then fully overwritten by k_gather.
    short* wp   = (short*)out1;

    // ws layout (bytes):
    char* w = (char*)d_ws;
    float* cnt       = (float*)w;                 w += (size_t)BT * NVOX * 4;       // 800000
    int*   nocc      = (int*)w;                   w += 256;
    int*   invmap    = (int*)w;                   w += (size_t)BT * NVOX * 4;       // 800000
    int*   ptvox     = (int*)w;                   w += (size_t)NPTS * 4;            // 135168
    int*   list      = (int*)w;                   w += (size_t)MAXS * 4;            // 135168
    float* compactM  = (float*)w;                 w += (size_t)MAXS * CG * 4;       // 6488064
    float* compact256= (float*)w;                 // MAXS*CO*4 = 34603008
    size_t zbytes = (size_t)BT * NVOX * 4 + 256 + (size_t)BT * NVOX * 4
                  + (size_t)NPTS * 4 + (size_t)MAXS * 4 + (size_t)MAXS * CG * 4;
    (void)hipMemsetAsync(d_ws, 0, zbytes, stream);      // ~8.4 MB

    k_count<<<NPTS / 256, 256, 0, stream>>>(centers, cnt, nocc, invmap, ptvox);
    k_mklist<<<(BT * NVOX + 255) / 256, 256, 0, stream>>>(invmap, list);
    k_scatterM<<<NPTS * CG / 256, 256, 0, stream>>>(feats, ptvox, invmap, compactM);
    k_packW<<<1, 256, 0, stream>>>(Wo2g, wp);
    k_volproj<<<1024, 256, 0, stream>>>(occ, wp, P);
    k_gather<<<NPTS * CG / 256, 256, 0, stream>>>(centers, P, bo2g, out1);
    k_gemm<<<(MAXS + 31) / 32, 256, 0, stream>>>(compactM, cnt, list, nocc, Wg2o, bg2o, compact256);
    k_writer<<<dim3((NVOX + 1023) / 1024, 8, BT), 256, 0, stream>>>(invmap, compact256, out0);
}

// Round 7
// 174.327 us; speedup vs baseline: 2.7470x; 1.0622x over previous
//
#include <hip/hip_runtime.h>
#include <hip/hip_bf16.h>

typedef float v4f __attribute__((ext_vector_type(4)));
typedef short bfrag8 __attribute__((ext_vector_type(8)));

// Problem constants (match reference)
constexpr int NXc = 100, NYc = 100, NZc = 10;
constexpr int NVOX = NZc * NYc * NXc;      // 100000
constexpr int CO = 256, CG = 48;
constexpr int BT = 2;
constexpr int NPT = 6 * 32 * 88;           // 16896 points per bt
constexpr int NPTS = BT * NPT;             // 33792
constexpr int MAXS = NPTS;                 // max occupied voxels
constexpr int NPAIR = NVOX / 32;           // 3125 32-vox pairs per bt
constexpr float GMX = -40.0f, GMY = -40.0f, GMZ = -2.0f;
constexpr float VOXEL = 0.8f;

static __device__ __forceinline__ short f2bf(float f) {
    __hip_bfloat16 h = __float2bfloat16(f);
    return __builtin_bit_cast(short, h);
}

// ---------------------------------------------------------------------------
// Pass 0: zero the scatter scratch (replaces pathologically slow runtime fill).
// ---------------------------------------------------------------------------
__global__ __launch_bounds__(256) void k_zero(v4f* __restrict__ p, int n16)
{
    v4f z = {0.f, 0.f, 0.f, 0.f};
    for (int i = blockIdx.x * 256 + threadIdx.x; i < n16; i += gridDim.x * 256)
        p[i] = z;
}

// ---------------------------------------------------------------------------
// Pass 1: per point -> voxel; count + assign compact slots.
// ---------------------------------------------------------------------------
__global__ __launch_bounds__(256) void k_count(
    const float* __restrict__ pts, float* __restrict__ cnt,
    int* __restrict__ nocc, int* __restrict__ invmap, int* __restrict__ ptvox)
{
    int pn = blockIdx.x * 256 + threadIdx.x;      // < NPTS (exact grid)
    float x = pts[pn * 3 + 0];
    float y = pts[pn * 3 + 1];
    float z = pts[pn * 3 + 2];
    int ix = (int)floorf((x - GMX) / VOXEL);
    int iy = (int)floorf((y - GMY) / VOXEL);
    int iz = (int)floorf((z - GMZ) / VOXEL);
    bool valid = (ix >= 0 && ix < NXc && iy >= 0 && iy < NYc && iz >= 0 && iz < NZc);
    if (!valid) { ptvox[pn] = -1; return; }
    int bt = pn / NPT;
    int btvox = bt * NVOX + iz * (NYc * NXc) + iy * NXc + ix;
    ptvox[pn] = btvox;
    float old = atomicAdd(&cnt[btvox], 1.0f);
    if (old == 0.0f) {
        int s = atomicAdd(nocc, 1);
        invmap[btvox] = s + 1;                    // 0 = empty
    }
}

// list[slot] = btvox needed by gemm for cnt lookup.
__global__ __launch_bounds__(256) void k_mklist(
    const int* __restrict__ invmap, int* __restrict__ list)
{
    int v = blockIdx.x * 256 + threadIdx.x;       // < BT*NVOX
    if (v >= BT * NVOX) return;
    int sp = invmap[v];
    if (sp) list[sp - 1] = v;
}

// ---------------------------------------------------------------------------
// Pass 2: scatter-add 48-dim features into compact mean buffer.
// ---------------------------------------------------------------------------
__global__ __launch_bounds__(256) void k_scatterM(
    const float* __restrict__ feats, const int* __restrict__ ptvox,
    const int* __restrict__ invmap, float* __restrict__ compactM)
{
    int idx = blockIdx.x * 256 + threadIdx.x;     // (pn)*CG + k, < NPTS*CG
    int k  = idx % CG;
    int pn = idx / CG;
    int bv = ptvox[pn];
    if (bv < 0) return;
    int slot = invmap[bv] - 1;
    atomicAdd(&compactM[(size_t)slot * CG + k], feats[idx]);
}

// ---------------------------------------------------------------------------
// Pass 3a: pack Wo2g^T into bf16 MFMA A-fragments.
// Fragment (s,gt): lane l slot j holds W[k][g], k = s*32 + (l>>4)*8 + j,
// g = gt*16 + (l&15).  wp[((s*3+gt)*64 + l)*8 + j].
// ---------------------------------------------------------------------------
__global__ __launch_bounds__(256) void k_packW(
    const float* __restrict__ Wo2g, short* __restrict__ wp)
{
    for (int e = threadIdx.x; e < 8 * 3 * 64 * 8; e += 256) {
        int j  = e & 7;
        int l  = (e >> 3) & 63;
        int ft = e >> 9;                          // s*3 + gt
        int s  = ft / 3, gt = ft - 3 * s;
        int k  = s * 32 + (l >> 4) * 8 + j;
        int g  = gt * 16 + (l & 15);
        wp[e] = f2bf(Wo2g[k * CG + g]);
    }
}

// ---------------------------------------------------------------------------
// Pass 3b: P[bt][vox][48] = occ[bt][:,vox]^T @ Wo2g via bf16 MFMA.
// One wave per 32-vox pair (2 tiles). W fragments hoisted to registers
// (24 frags = 96 VGPR, loaded once per wave); q folded into base pointer.
// C/D layout (m89): col = lane&15 (vox), row = (lane>>4)*4+reg (g).
// ---------------------------------------------------------------------------
__global__ __launch_bounds__(256) void k_volproj(
    const float* __restrict__ occ, const short* __restrict__ wp,
    float* __restrict__ P)
{
    int gwid = (blockIdx.x * 256 + threadIdx.x) >> 6;
    if (gwid >= BT * NPAIR) return;
    int l = threadIdx.x & 63;
    int q = l >> 4, r = l & 15;
    const bfrag8* wf = reinterpret_cast<const bfrag8*>(wp);
    bfrag8 wfr[8][3];
#pragma unroll
    for (int s = 0; s < 8; ++s)
#pragma unroll
        for (int gt = 0; gt < 3; ++gt)
            wfr[s][gt] = wf[(s * 3 + gt) * 64 + l];
    int bt = gwid / NPAIR;
    int vox0 = (gwid - bt * NPAIR) * 32;
    const float* b0 = occ + (size_t)bt * CO * NVOX + (size_t)q * 8 * NVOX + vox0 + r;
    v4f acc0[3] = {{0.f,0.f,0.f,0.f},{0.f,0.f,0.f,0.f},{0.f,0.f,0.f,0.f}};
    v4f acc1[3] = {{0.f,0.f,0.f,0.f},{0.f,0.f,0.f,0.f},{0.f,0.f,0.f,0.f}};
#pragma unroll
    for (int s = 0; s < 8; ++s) {
        float t0[8], t1[8];
#pragma unroll
        for (int j = 0; j < 8; ++j) {
            const float* a = b0 + (size_t)(s * 32 + j) * NVOX;
            t0[j] = a[0];
            t1[j] = a[16];
        }
        bfrag8 bf0, bf1;
#pragma unroll
        for (int j = 0; j < 8; ++j) { bf0[j] = f2bf(t0[j]); bf1[j] = f2bf(t1[j]); }
#pragma unroll
        for (int gt = 0; gt < 3; ++gt) {
            acc0[gt] = __builtin_amdgcn_mfma_f32_16x16x32_bf16(wfr[s][gt], bf0, acc0[gt], 0, 0, 0);
            acc1[gt] = __builtin_amdgcn_mfma_f32_16x16x32_bf16(wfr[s][gt], bf1, acc1[gt], 0, 0, 0);
        }
    }
    float* o0 = P + ((size_t)bt * NVOX + vox0 + r) * CG + q * 4;
    float* o1 = o0 + (size_t)16 * CG;
#pragma unroll
    for (int gt = 0; gt < 3; ++gt) {
        *reinterpret_cast<v4f*>(o0 + 16 * gt) = acc0[gt];
        *reinterpret_cast<v4f*>(o1 + 16 * gt) = acc1[gt];
    }
}

// ---------------------------------------------------------------------------
// Pass 4: trilinear gather from P + bias -> occ_to_gs output.
// ---------------------------------------------------------------------------
__global__ __launch_bounds__(256) void k_gather(
    const float* __restrict__ pts, const float* __restrict__ P,
    const float* __restrict__ bo2g, float* __restrict__ out1)
{
    int idx = blockIdx.x * 256 + threadIdx.x;     // (pn)*CG + g
    int g  = idx % CG;
    int pn = idx / CG;
    int bt = pn / NPT;
    float x = pts[pn * 3 + 0];
    float y = pts[pn * 3 + 1];
    float z = pts[pn * 3 + 2];
    float gx = (x - GMX) / 80.0f * 2.0f - 1.0f;
    float gy = (y - GMY) / 80.0f * 2.0f - 1.0f;
    float gz = (z - GMZ) / 8.0f  * 2.0f - 1.0f;
    float px = ((gx + 1.0f) * (float)NXc - 1.0f) * 0.5f;
    float py = ((gy + 1.0f) * (float)NYc - 1.0f) * 0.5f;
    float pz = ((gz + 1.0f) * (float)NZc - 1.0f) * 0.5f;
    float fx = floorf(px), fy = floorf(py), fz = floorf(pz);
    float rx = px - fx, ry = py - fy, rz = pz - fz;
    int x0 = (int)fx, y0 = (int)fy, z0 = (int)fz;
    float acc = bo2g[g];
    const float* Pb = P + (size_t)bt * NVOX * CG;
#pragma unroll
    for (int dz = 0; dz <= 1; ++dz) {
        int zi = z0 + dz;
        if (zi < 0 || zi >= NZc) continue;
        float wz = dz ? rz : 1.0f - rz;
#pragma unroll
        for (int dy = 0; dy <= 1; ++dy) {
            int yi = y0 + dy;
            if (yi < 0 || yi >= NYc) continue;
            float wy = dy ? ry : 1.0f - ry;
#pragma unroll
            for (int dx = 0; dx <= 1; ++dx) {
                int xi = x0 + dx;
                if (xi < 0 || xi >= NXc) continue;
                float wx = dx ? rx : 1.0f - rx;
                float w = (wx * wy) * wz;
                int lin = zi * (NYc * NXc) + yi * NXc + xi;
                acc = fmaf(w, Pb[(size_t)lin * CG + g], acc);
            }
        }
    }
    out1[idx] = acc;
}

// ---------------------------------------------------------------------------
// Pass 5: sparse GEMM — compact256[slot][256] = mean[slot][48] @ Wg2o + b.
// ---------------------------------------------------------------------------
__global__ __launch_bounds__(256) void k_gemm(
    const float* __restrict__ compactM, const float* __restrict__ cnt,
    const int* __restrict__ list, const int* __restrict__ noccp,
    const float* __restrict__ Wg2o, const float* __restrict__ bg2o,
    float* __restrict__ compact256)
{
    int nocc = *noccp;
    int s0 = blockIdx.x * 32;
    if (s0 >= nocc) return;                      // uniform per block
    __shared__ float Wl[CG * CO];                // 48 KB, [k][c]
    __shared__ float Ml[32 * CG];                // 6 KB means
    for (int j = threadIdx.x; j < CG * CO; j += 256) Wl[j] = Wg2o[j];
    for (int j = threadIdx.x; j < 32 * CG; j += 256) {
        int v = j / CG, k = j - v * CG;
        int slot = s0 + v;
        float m = 0.f;
        if (slot < nocc) {
            int btvox = list[slot];
            m = compactM[(size_t)slot * CG + k] / cnt[btvox];
        }
        Ml[j] = m;
    }
    __syncthreads();
    int wid = threadIdx.x >> 6, l = threadIdx.x & 63;
    int vb = wid * 8;
    float4 bias = *reinterpret_cast<const float4*>(&bg2o[4 * l]);
    float acc[8][4];
#pragma unroll
    for (int v = 0; v < 8; ++v) {
        acc[v][0] = bias.x; acc[v][1] = bias.y; acc[v][2] = bias.z; acc[v][3] = bias.w;
    }
    for (int k = 0; k < CG; k += 4) {
        float4 w0 = *reinterpret_cast<const float4*>(&Wl[(k + 0) * CO + 4 * l]);
        float4 w1 = *reinterpret_cast<const float4*>(&Wl[(k + 1) * CO + 4 * l]);
        float4 w2 = *reinterpret_cast<const float4*>(&Wl[(k + 2) * CO + 4 * l]);
        float4 w3 = *reinterpret_cast<const float4*>(&Wl[(k + 3) * CO + 4 * l]);
#pragma unroll
        for (int v = 0; v < 8; ++v) {
            float4 m4 = *reinterpret_cast<const float4*>(&Ml[(vb + v) * CG + k]);
            acc[v][0] = fmaf(m4.x, w0.x, acc[v][0]);
            acc[v][1] = fmaf(m4.x, w0.y, acc[v][1]);
            acc[v][2] = fmaf(m4.x, w0.z, acc[v][2]);
            acc[v][3] = fmaf(m4.x, w0.w, acc[v][3]);
            acc[v][0] = fmaf(m4.y, w1.x, acc[v][0]);
            acc[v][1] = fmaf(m4.y, w1.y, acc[v][1]);
            acc[v][2] = fmaf(m4.y, w1.z, acc[v][2]);
            acc[v][3] = fmaf(m4.y, w1.w, acc[v][3]);
            acc[v][0] = fmaf(m4.z, w2.x, acc[v][0]);
            acc[v][1] = fmaf(m4.z, w2.y, acc[v][1]);
            acc[v][2] = fmaf(m4.z, w2.z, acc[v][2]);
            acc[v][3] = fmaf(m4.z, w2.w, acc[v][3]);
            acc[v][0] = fmaf(m4.w, w3.x, acc[v][0]);
            acc[v][1] = fmaf(m4.w, w3.y, acc[v][1]);
            acc[v][2] = fmaf(m4.w, w3.z, acc[v][2]);
            acc[v][3] = fmaf(m4.w, w3.w, acc[v][3]);
        }
    }
#pragma unroll
    for (int v = 0; v < 8; ++v) {
        int slot = s0 + vb + v;
        if (slot < nocc) {
            float4 rr; rr.x = acc[v][0]; rr.y = acc[v][1]; rr.z = acc[v][2]; rr.w = acc[v][3];
            *reinterpret_cast<float4*>(&compact256[(size_t)slot * CO + 4 * l]) = rr;
        }
    }
}

// ---------------------------------------------------------------------------
// Pass 6: dense writer. Thread -> 4 consecutive vox; loop 32 channels.
// ---------------------------------------------------------------------------
__global__ __launch_bounds__(256) void k_writer(
    const int* __restrict__ invmap, const float* __restrict__ compact256,
    float* __restrict__ out0)
{
    int bt = blockIdx.z;
    int c0 = blockIdx.y * 32;
    int v0 = blockIdx.x * 1024 + threadIdx.x * 4;
    if (v0 >= NVOX) return;
    int4 sp = *reinterpret_cast<const int4*>(&invmap[bt * NVOX + v0]);
    const float* r0 = compact256 + (size_t)(sp.x - 1) * CO;
    const float* r1 = compact256 + (size_t)(sp.y - 1) * CO;
    const float* r2 = compact256 + (size_t)(sp.z - 1) * CO;
    const float* r3 = compact256 + (size_t)(sp.w - 1) * CO;
    float* ob = out0 + (size_t)bt * CO * NVOX + (size_t)c0 * NVOX + v0;
#pragma unroll 4
    for (int ci = 0; ci < 32; ++ci) {
        int c = c0 + ci;
        v4f val;
        val.x = sp.x ? r0[c] : 0.f;
        val.y = sp.y ? r1[c] : 0.f;
        val.z = sp.z ? r2[c] : 0.f;
        val.w = sp.w ? r3[c] : 0.f;
        __builtin_nontemporal_store(val, reinterpret_cast<v4f*>(ob + (size_t)ci * NVOX));
    }
}

// ---------------------------------------------------------------------------
extern "C" void kernel_launch(void* const* d_in, const int* in_sizes, int n_in,
                              void* d_out, int out_size, void* d_ws, size_t ws_size,
                              hipStream_t stream)
{
    const float* centers = (const float*)d_in[0];
    const float* feats   = (const float*)d_in[1];
    const float* occ     = (const float*)d_in[2];
    const float* Wg2o    = (const float*)d_in[3];
    const float* bg2o    = (const float*)d_in[4];
    const float* Wo2g    = (const float*)d_in[5];
    const float* bo2g    = (const float*)d_in[6];

    float* out  = (float*)d_out;
    float* out0 = out;                                   // [BT][CO][NVOX]
    float* out1 = out + (size_t)BT * CO * NVOX;          // [BT][NPT][CG]
    // P in tail of out0: written by volproj, read by gather, overwritten by writer.
    float* P    = out0 + (size_t)BT * CO * NVOX - (size_t)BT * NVOX * CG;
    // Packed bf16 W fragments live at the head of out1 (24 KB): written by
    // k_packW, read by k_volproj, then fully overwritten by k_gather.
    short* wp   = (short*)out1;

    // ws layout (bytes):
    char* w = (char*)d_ws;
    float* cnt       = (float*)w;                 w += (size_t)BT * NVOX * 4;       // 800000
    int*   nocc      = (int*)w;                   w += 256;
    int*   invmap    = (int*)w;                   w += (size_t)BT * NVOX * 4;       // 800000
    int*   ptvox     = (int*)w;                   w += (size_t)NPTS * 4;            // 135168
    int*   list      = (int*)w;                   w += (size_t)MAXS * 4;            // 135168
    float* compactM  = (float*)w;                 w += (size_t)MAXS * CG * 4;       // 6488064
    float* compact256= (float*)w;                 // MAXS*CO*4 = 34603008
    size_t zbytes = (size_t)BT * NVOX * 4 + 256 + (size_t)BT * NVOX * 4
                  + (size_t)NPTS * 4 + (size_t)MAXS * 4 + (size_t)MAXS * CG * 4;
    // 8,358,656 bytes = 522,416 x 16B; custom zero kernel (runtime fill was 119us!)
    k_zero<<<1024, 256, 0, stream>>>((v4f*)d_ws, (int)(zbytes / 16));

    k_count<<<NPTS / 256, 256, 0, stream>>>(centers, cnt, nocc, invmap, ptvox);
    k_mklist<<<(BT * NVOX + 255) / 256, 256, 0, stream>>>(invmap, list);
    k_scatterM<<<NPTS * CG / 256, 256, 0, stream>>>(feats, ptvox, invmap, compactM);
    k_packW<<<1, 256, 0, stream>>>(Wo2g, wp);
    k_volproj<<<(BT * NPAIR + 3) / 4, 256, 0, stream>>>(occ, wp, P);
    k_gather<<<NPTS * CG / 256, 256, 0, stream>>>(centers, P, bo2g, out1);
    k_gemm<<<(MAXS + 31) / 32, 256, 0, stream>>>(compactM, cnt, list, nocc, Wg2o, bg2o, compact256);
    k_writer<<<dim3((NVOX + 1023) / 1024, 8, BT), 256, 0, stream>>>(invmap, compact256, out0);
}